// Round 1
// baseline (152.292 us; speedup 1.0000x reference)
//
#include <hip/hip_runtime.h>
#include <stdint.h>

// Otsu-variant threshold, 24 rows x 2^20 px, float32 in/out.
// Strategy: emulate the reference pipeline at float64 precision (the "np"
// high-precision reference). No sort: searchsorted prefix sums via 256-bin
// histograms with deterministic int64 fixed-point accumulation (scale 2^40).

#define ROWS 24
#define NPIX (1 << 20)
#define NBINS 256
#define BLOCKS_PER_ROW 64
#define CHUNK (NPIX / BLOCKS_PER_ROW)  // 16384 elems per block
#define MAX_TRY 25                     // int(256*0.1)

static constexpr double kScale = 1099511627776.0;  // 2^40
static constexpr double Nd = 1048576.0;

// ws layout (bytes)
#define OFF_ROWMIN 0                   // u32[32] (float bits, init 0x7f7f7f7f)
#define OFF_ROWMAX 128                 // u32[32] (init 0)
#define OFF_WIDTH  256                 // double
#define OFF_FINAL  384                 // double[32]
#define OFF_THRESH 1024                // double[256]
#define OFF_CF     4096                // u32 [24][256] floor-bin counts (w0)
#define OFF_CJ     (OFF_CF + ROWS*NBINS*4)
#define OFF_S1     (OFF_CJ + ROWS*NBINS*4)      // i64 fixed-point sum(xs)
#define OFF_S2     (OFF_S1 + ROWS*NBINS*8)      // i64 fixed-point sum(xs^2)
#define OFF_ICV    (OFF_S2 + ROWS*NBINS*8)      // double [24][256]
#define WS_TOTAL   (OFF_ICV + ROWS*NBINS*8)     // ~200 KB

__global__ __launch_bounds__(256) void k_minmax(const float* __restrict__ x,
                                                unsigned* __restrict__ rowmin,
                                                unsigned* __restrict__ rowmax) {
  int row = blockIdx.x / BLOCKS_PER_ROW;
  int sub = blockIdx.x % BLOCKS_PER_ROW;
  const float4* p = (const float4*)(x + (size_t)row * NPIX + (size_t)sub * CHUNK);
  float mn = 3.4e38f, mx = 0.0f;
  for (int i = threadIdx.x; i < CHUNK / 4; i += 256) {
    float4 v = p[i];
    mn = fminf(mn, fminf(fminf(v.x, v.y), fminf(v.z, v.w)));
    mx = fmaxf(mx, fmaxf(fmaxf(v.x, v.y), fmaxf(v.z, v.w)));
  }
  __shared__ float smn[4], smx[4];
  for (int o = 32; o; o >>= 1) {
    mn = fminf(mn, __shfl_down(mn, o));
    mx = fmaxf(mx, __shfl_down(mx, o));
  }
  int wave = threadIdx.x >> 6;
  if ((threadIdx.x & 63) == 0) { smn[wave] = mn; smx[wave] = mx; }
  __syncthreads();
  if (threadIdx.x == 0) {
    for (int w = 1; w < 4; ++w) { mn = fminf(mn, smn[w]); mx = fmaxf(mx, smx[w]); }
    // x >= 0 so uint bit-pattern ordering == float ordering
    atomicMin(&rowmin[row], __float_as_uint(mn));
    atomicMax(&rowmax[row], __float_as_uint(mx));
  }
}

__global__ void k_prep(const unsigned* __restrict__ rowmin,
                       const unsigned* __restrict__ rowmax,
                       double* __restrict__ thresh, double* __restrict__ widthp) {
  __shared__ double sw;
  if (threadIdx.x == 0) {
    double g = 0.0;
    for (int r = 0; r < ROWS; ++r) {
      double d = (double)__uint_as_float(rowmax[r]) - (double)__uint_as_float(rowmin[r]);
      g = fmax(g, d);
    }
    sw = g / 256.0;  // exact (power of 2)
    *widthp = sw;
  }
  __syncthreads();
  int t = threadIdx.x;  // 256 threads
  thresh[t] = (double)(t + 1) * sw;  // == linspace edge[t+1] in f64
}

__global__ __launch_bounds__(256) void k_hist(const float* __restrict__ x,
    const unsigned* __restrict__ rowmin,
    const double* __restrict__ threshG, const double* __restrict__ widthp,
    unsigned* __restrict__ gcf, unsigned* __restrict__ gcj,
    unsigned long long* __restrict__ gs1, unsigned long long* __restrict__ gs2) {
  __shared__ unsigned scf[NBINS], scj[NBINS];
  __shared__ unsigned long long ss1[NBINS], ss2[NBINS];
  __shared__ double sth[NBINS];
  int t = threadIdx.x;
  scf[t] = 0u; scj[t] = 0u; ss1[t] = 0ull; ss2[t] = 0ull;
  sth[t] = threshG[t];
  __syncthreads();
  int row = blockIdx.x / BLOCKS_PER_ROW;
  int sub = blockIdx.x % BLOCKS_PER_ROW;
  double rmin = (double)__uint_as_float(rowmin[row]);
  double w = *widthp;
  const float4* p = (const float4*)(x + (size_t)row * NPIX + (size_t)sub * CHUNK);
  for (int i = threadIdx.x; i < CHUNK / 4; i += 256) {
    float4 v = p[i];
    float vv[4] = {v.x, v.y, v.z, v.w};
#pragma unroll
    for (int c = 0; c < 4; ++c) {
      double xs = (double)vv[c] - rmin;  // exact in f64 (both are f32 values)
      double q = xs / w;                 // IEEE f64 division, matches reference
      int b = (int)floor(q);
      b = b < 0 ? 0 : (b > 255 ? 255 : b);
      // j = searchsorted(thresh, xs): smallest t with xs <= thresh[t].
      // floor-bin hint b is within 1 of j.
      int j = b;
      if (xs > sth[j]) { if (j < 255) ++j; }
      else if (j > 0 && xs <= sth[j - 1]) --j;
      atomicAdd(&scf[b], 1u);
      atomicAdd(&scj[j], 1u);
      unsigned long long v1 = (unsigned long long)llrint(xs * kScale);
      unsigned long long v2 = (unsigned long long)llrint(xs * xs * kScale);
      atomicAdd(&ss1[j], v1);
      atomicAdd(&ss2[j], v2);
    }
  }
  __syncthreads();
  atomicAdd(&gcf[row * NBINS + t], scf[t]);
  atomicAdd(&gcj[row * NBINS + t], scj[t]);
  atomicAdd(&gs1[row * NBINS + t], ss1[t]);
  atomicAdd(&gs2[row * NBINS + t], ss2[t]);
}

__global__ __launch_bounds__(256) void k_icv(const unsigned* __restrict__ gcf,
    const unsigned* __restrict__ gcj,
    const unsigned long long* __restrict__ gs1,
    const unsigned long long* __restrict__ gs2,
    double* __restrict__ icv_out) {
  int r = blockIdx.x, t = threadIdx.x;
  __shared__ unsigned long long scf[NBINS], scj[NBINS], ss1[NBINS], ss2[NBINS];
  scf[t] = gcf[r * NBINS + t]; scj[t] = gcj[r * NBINS + t];
  ss1[t] = gs1[r * NBINS + t]; ss2[t] = gs2[r * NBINS + t];
  __syncthreads();
  // inclusive Hillis-Steele scan over bins
  for (int o = 1; o < NBINS; o <<= 1) {
    unsigned long long a = 0, b = 0, c = 0, d = 0;
    if (t >= o) { a = scf[t - o]; b = scj[t - o]; c = ss1[t - o]; d = ss2[t - o]; }
    __syncthreads();
    if (t >= o) { scf[t] += a; scj[t] += b; ss1[t] += c; ss2[t] += d; }
    __syncthreads();
  }
  const double dNAN = __builtin_nan("");
  double total1 = (double)ss1[NBINS - 1] / kScale;
  double total2 = (double)ss2[NBINS - 1] / kScale;
  double mean = total1 / Nd;
  double tot1 = total1 - Nd * mean;              // sum of centered vals (~0)
  double tot2 = total2 - Nd * mean * mean;       // sum of centered squares
  double n0 = (double)scj[t];
  double n1 = Nd - n0;
  double s1raw = (double)ss1[t] / kScale;
  double s2raw = (double)ss2[t] / kScale;
  double S1 = s1raw - n0 * mean;
  double S2 = s2raw - 2.0 * mean * s1raw + n0 * mean * mean;
  double mu0 = (scj[t] > 1ull) ? (S2 - S1 * S1 / n0) / (n0 - 1.0) : dNAN;
  double S1b = tot1 - S1, S2b = tot2 - S2;
  double mu1 = (n1 > 1.0) ? (S2b - S1b * S1b / n1) / (n1 - 1.0) : dNAN;
  double w0 = (double)scf[t] / Nd, w1 = 1.0 - w0;
  double dd = mu0 - mu1;
  icv_out[r * NBINS + t] = w0 * w1 * dd * dd;  // NaN propagates (n<=1 cases)
}

__global__ __launch_bounds__(256) void k_scan(const double* __restrict__ icv,
    const double* __restrict__ thresh, const unsigned* __restrict__ rowmin,
    double* __restrict__ finalt) {
  __shared__ double sicv[ROWS * NBINS];  // 48 KB
  __shared__ double sth[NBINS];
  for (int i = threadIdx.x; i < ROWS * NBINS; i += 256) sicv[i] = icv[i];
  sth[threadIdx.x] = thresh[threadIdx.x];
  __syncthreads();
  if (threadIdx.x >= 64) return;  // scan runs on wave 0 only
  int r = threadIdx.x;
  bool active = r < ROWS;
  double maxicv = 0.0, best = 0.0;
  int no_upd = 0;
  bool stopped = false;
  for (int t = 0; t < NBINS; ++t) {
    double v = active ? sicv[r * NBINS + t] : -1.0;
    bool upd = active && !stopped && (v > maxicv);  // NaN -> false, like ref
    if (upd) { maxicv = v; best = sth[t]; }
    unsigned long long bal = __ballot(upd);
    if (bal != 0ull) no_upd = 0; else ++no_upd;      // global "any row updated"
    if (no_upd >= MAX_TRY) stopped = true;           // applies from next t
  }
  if (active) finalt[r] = best + (double)__uint_as_float(rowmin[r]);
}

__global__ __launch_bounds__(256) void k_out(const float* __restrict__ x,
                                             const double* __restrict__ finalt,
                                             float* __restrict__ out) {
  size_t i = (size_t)blockIdx.x * blockDim.x + threadIdx.x;
  size_t stride = (size_t)gridDim.x * blockDim.x;
  const float4* xin = (const float4*)x;
  float4* o = (float4*)out;
  size_t n4 = (size_t)ROWS * NPIX / 4;
  for (; i < n4; i += stride) {
    int row = (int)(i >> 18);  // 2^18 float4 per row
    double ft = finalt[row];
    float4 v = xin[i];
    float4 rr;
    rr.x = ((double)v.x < ft) ? 0.0f : v.x;
    rr.y = ((double)v.y < ft) ? 0.0f : v.y;
    rr.z = ((double)v.z < ft) ? 0.0f : v.z;
    rr.w = ((double)v.w < ft) ? 0.0f : v.w;
    o[i] = rr;
  }
}

extern "C" void kernel_launch(void* const* d_in, const int* in_sizes, int n_in,
                              void* d_out, int out_size, void* d_ws, size_t ws_size,
                              hipStream_t stream) {
  const float* x = (const float*)d_in[0];
  float* out = (float*)d_out;
  char* ws = (char*)d_ws;
  unsigned* rowmin = (unsigned*)(ws + OFF_ROWMIN);
  unsigned* rowmax = (unsigned*)(ws + OFF_ROWMAX);
  double* widthp = (double*)(ws + OFF_WIDTH);
  double* finalt = (double*)(ws + OFF_FINAL);
  double* thresh = (double*)(ws + OFF_THRESH);
  unsigned* gcf = (unsigned*)(ws + OFF_CF);
  unsigned* gcj = (unsigned*)(ws + OFF_CJ);
  unsigned long long* gs1 = (unsigned long long*)(ws + OFF_S1);
  unsigned long long* gs2 = (unsigned long long*)(ws + OFF_S2);
  double* icv = (double*)(ws + OFF_ICV);

  hipMemsetAsync(d_ws, 0, WS_TOTAL, stream);
  hipMemsetAsync(ws + OFF_ROWMIN, 0x7f, 128, stream);  // rowmin init = 3.39e38

  k_minmax<<<ROWS * BLOCKS_PER_ROW, 256, 0, stream>>>(x, rowmin, rowmax);
  k_prep<<<1, 256, 0, stream>>>(rowmin, rowmax, thresh, widthp);
  k_hist<<<ROWS * BLOCKS_PER_ROW, 256, 0, stream>>>(x, rowmin, thresh, widthp,
                                                    gcf, gcj, gs1, gs2);
  k_icv<<<ROWS, 256, 0, stream>>>(gcf, gcj, gs1, gs2, icv);
  k_scan<<<1, 256, 0, stream>>>(icv, thresh, rowmin, finalt);
  k_out<<<3072, 256, 0, stream>>>(x, finalt, out);
}

// Round 2
// 139.637 us; speedup vs baseline: 1.0906x; 1.0906x over previous
//
#include <hip/hip_runtime.h>
#include <stdint.h>

// Otsu-variant threshold, 24 rows x 2^20 px, float32 in/out.
// f64-exact emulation of the reference pipeline; searchsorted prefix sums via
// 256-bin histograms with 2^40 fixed-point int64 accumulation (deterministic).
// R2: 3 LDS atomics/elem (combined count + rare corrections), arithmetic edge
// recompute, k_prep/k_icv/k_scan fused away -> 5 dispatches.

#define ROWS 24
#define NPIX (1 << 20)
#define NBINS 256
#define BPR 64                      // blocks per row
#define CHUNK (NPIX / BPR)          // 16384 elems per block
#define MAX_TRY 25                  // int(256*0.1)

static constexpr double kScale = 1099511627776.0;  // 2^40
static constexpr double Nd = 1048576.0;

// ws layout (bytes); everything below WS_TOTAL is memset(0) once
#define OFF_MINNOT 0                // u32[24]: atomicMax of ~float_bits (init 0)
#define OFF_MAXB   128              // u32[24]: atomicMax of float_bits (init 0)
#define OFF_FINAL  256              // double[24] final thresholds
#define OFF_CNT    512              // u32 [24][256] counts keyed by searchsorted j
#define OFF_COR    (OFF_CNT + ROWS*NBINS*4)   // i32 [24][256] floor-bin corrections
#define OFF_S1     (OFF_COR + ROWS*NBINS*4)   // u64 fixed-point sum(xs), keyed by j
#define OFF_S2     (OFF_S1 + ROWS*NBINS*8)    // u64 fixed-point sum(xs^2)
#define WS_TOTAL   (OFF_S2 + ROWS*NBINS*8)    // ~148 KB

__device__ __forceinline__ double wave_gmax(const unsigned* __restrict__ minnot,
                                            const unsigned* __restrict__ maxb,
                                            int lane) {
  // lanes 0..23 load one row each; max-reduce over lanes 0..31 -> lane 0
  double d = 0.0;
  if (lane < ROWS) {
    d = (double)__uint_as_float(maxb[lane]) - (double)__uint_as_float(~minnot[lane]);
  }
  for (int o = 16; o; o >>= 1) d = fmax(d, __shfl_down(d, o));
  return d;  // valid in lane 0
}

__global__ __launch_bounds__(256) void k_minmax(const float* __restrict__ x,
                                                unsigned* __restrict__ minnot,
                                                unsigned* __restrict__ maxb) {
  int row = blockIdx.x / BPR;
  int sub = blockIdx.x % BPR;
  const float4* p = (const float4*)(x + (size_t)row * NPIX + (size_t)sub * CHUNK);
  float mn = 3.4e38f, mx = 0.0f;
  for (int i = threadIdx.x; i < CHUNK / 4; i += 256) {
    float4 v = p[i];
    mn = fminf(mn, fminf(fminf(v.x, v.y), fminf(v.z, v.w)));
    mx = fmaxf(mx, fmaxf(fmaxf(v.x, v.y), fmaxf(v.z, v.w)));
  }
  __shared__ float smn[4], smx[4];
  for (int o = 32; o; o >>= 1) {
    mn = fminf(mn, __shfl_down(mn, o));
    mx = fmaxf(mx, __shfl_down(mx, o));
  }
  int wave = threadIdx.x >> 6;
  if ((threadIdx.x & 63) == 0) { smn[wave] = mn; smx[wave] = mx; }
  __syncthreads();
  if (threadIdx.x == 0) {
    for (int w = 1; w < 4; ++w) { mn = fminf(mn, smn[w]); mx = fmaxf(mx, smx[w]); }
    // x >= 0 so uint bit-pattern ordering == float ordering; ~bits flips it
    atomicMax(&minnot[row], ~__float_as_uint(mn));
    atomicMax(&maxb[row], __float_as_uint(mx));
  }
}

__global__ __launch_bounds__(256) void k_hist(const float* __restrict__ x,
    const unsigned* __restrict__ minnot, const unsigned* __restrict__ maxb,
    unsigned* __restrict__ gcnt, int* __restrict__ gcor,
    unsigned long long* __restrict__ gs1, unsigned long long* __restrict__ gs2) {
  __shared__ unsigned hc[NBINS];
  __shared__ int hcor[NBINS];
  __shared__ unsigned long long h1[NBINS], h2[NBINS];
  __shared__ double s_w, s_rmin;
  int t = threadIdx.x;
  hc[t] = 0u; hcor[t] = 0; h1[t] = 0ull; h2[t] = 0ull;
  int row = blockIdx.x / BPR;
  int sub = blockIdx.x % BPR;
  if (t < 64) {
    double g = wave_gmax(minnot, maxb, t);
    if (t == 0) {
      s_w = g / 256.0;  // exact (pow2); == reference gmax/NBINS in f64
      s_rmin = (double)__uint_as_float(~minnot[row]);
    }
  }
  __syncthreads();
  double w = s_w, rmin = s_rmin;
  const float4* p = (const float4*)(x + (size_t)row * NPIX + (size_t)sub * CHUNK);
  for (int i = threadIdx.x; i < CHUNK / 4; i += 256) {
    float4 v = p[i];
    float vv[4] = {v.x, v.y, v.z, v.w};
#pragma unroll
    for (int c = 0; c < 4; ++c) {
      double xs = (double)vv[c] - rmin;  // exact in f64
      double q = xs / w;                 // IEEE f64 div, matches np reference
      int b = (int)q;                    // q >= 0 -> trunc == floor
      b = b > 255 ? 255 : b;
      // j = searchsorted(upper_edges, xs): smallest t with xs <= (t+1)*w.
      // Edges recomputed bit-exactly: thresh[t] = fl((t+1)*w).
      double elo = (double)b * w;        // == thresh[b-1]
      double ehi = (double)(b + 1) * w;  // == thresh[b]
      int j = b;
      if (xs > ehi) { if (b < 255) j = b + 1; }
      else if (b > 0 && xs <= elo) j = b - 1;
      atomicAdd(&hc[j], 1u);
      if (j != b) {                       // exact-boundary elements only (rare)
        atomicAdd(&hcor[b], 1);
        atomicAdd(&hcor[j], -1);
      }
      unsigned long long a1 = (unsigned long long)llrint(xs * kScale);
      unsigned long long a2 = (unsigned long long)llrint(xs * xs * kScale);
      atomicAdd(&h1[j], a1);
      atomicAdd(&h2[j], a2);
    }
  }
  __syncthreads();
  atomicAdd(&gcnt[row * NBINS + t], hc[t]);
  if (hcor[t] != 0) atomicAdd(&gcor[row * NBINS + t], hcor[t]);
  atomicAdd(&gs1[row * NBINS + t], h1[t]);
  atomicAdd(&gs2[row * NBINS + t], h2[t]);
}

// One block, 1024 threads: per-wave prefix scans (2 rows/wave), icv into LDS,
// then the reference's early-stopped global argmax scan on wave 0.
__global__ __launch_bounds__(1024) void k_icv_scan(
    const unsigned* __restrict__ gcnt, const int* __restrict__ gcor,
    const unsigned long long* __restrict__ gs1,
    const unsigned long long* __restrict__ gs2,
    const unsigned* __restrict__ minnot, const unsigned* __restrict__ maxb,
    double* __restrict__ finalt) {
  __shared__ double sicv[ROWS * NBINS];  // 48 KB
  __shared__ double s_w;
  int tid = threadIdx.x;
  int wave = tid >> 6, lane = tid & 63;
  if (tid < 64) {
    double g = wave_gmax(minnot, maxb, lane);
    if (tid == 0) s_w = g / 256.0;
  }
  __syncthreads();

  const double dNAN = __builtin_nan("");
#pragma unroll
  for (int pass = 0; pass < 2; ++pass) {
    int r = (pass == 0) ? wave : 16 + wave;
    if (pass == 1 && wave >= 8) break;
    int base = r * NBINS + lane * 4;
    unsigned cj[4]; int cr[4];
    *(uint4*)cj = *(const uint4*)&gcnt[base];
    *(int4*)cr = *(const int4*)&gcor[base];
    unsigned long long s1v[4], s2v[4];
#pragma unroll
    for (int k = 0; k < 4; ++k) { s1v[k] = gs1[base + k]; s2v[k] = gs2[base + k]; }
    // lane-local inclusive scans; P packs cumj (lo32) and cumf (hi32)
    unsigned long long P[4], A[4], B[4];
    unsigned long long rp = 0, ra = 0, rb = 0;
#pragma unroll
    for (int k = 0; k < 4; ++k) {
      unsigned cf = cj[k] + (unsigned)cr[k];
      rp += (unsigned long long)cj[k] | ((unsigned long long)cf << 32);
      ra += s1v[k]; rb += s2v[k];
      P[k] = rp; A[k] = ra; B[k] = rb;
    }
    // wave-level inclusive scan of lane totals
    unsigned long long tp = rp, ta = ra, tb = rb;
    for (int o = 1; o < 64; o <<= 1) {
      unsigned long long up = __shfl_up(tp, o);
      unsigned long long ua = __shfl_up(ta, o);
      unsigned long long ub = __shfl_up(tb, o);
      if (lane >= o) { tp += up; ta += ua; tb += ub; }
    }
    unsigned long long totP = __shfl(tp, 63);
    unsigned long long totA = __shfl(ta, 63);
    unsigned long long totB = __shfl(tb, 63);
    unsigned long long ep = tp - rp, ea = ta - ra, eb = tb - rb;  // exclusive

    double total1 = (double)totA / kScale;
    double total2 = (double)totB / kScale;
    double mean = total1 / Nd;
    double tot1 = total1 - Nd * mean;
    double tot2 = total2 - Nd * mean * mean;
    (void)totP;
#pragma unroll
    for (int k = 0; k < 4; ++k) {
      unsigned long long Pk = P[k] + ep;
      unsigned long long cjc = Pk & 0xffffffffull;
      unsigned long long cfc = Pk >> 32;
      double n0 = (double)cjc;
      double n1 = Nd - n0;
      double s1raw = (double)(A[k] + ea) / kScale;
      double s2raw = (double)(B[k] + eb) / kScale;
      double S1 = s1raw - n0 * mean;
      double S2 = s2raw - 2.0 * mean * s1raw + n0 * mean * mean;
      double mu0 = (cjc > 1ull) ? (S2 - S1 * S1 / n0) / (n0 - 1.0) : dNAN;
      double S1b = tot1 - S1, S2b = tot2 - S2;
      double mu1 = (n1 > 1.0) ? (S2b - S1b * S1b / n1) / (n1 - 1.0) : dNAN;
      double w0 = (double)cfc / Nd, w1 = 1.0 - w0;
      double dd = mu0 - mu1;
      sicv[r * NBINS + lane * 4 + k] = w0 * w1 * dd * dd;  // NaN propagates
    }
  }
  __syncthreads();

  if (tid < 64) {
    int r = tid;
    bool active = r < ROWS;
    double w = s_w;
    double maxicv = 0.0, best = 0.0;
    int no_upd = 0;
    bool stopped = false;
    for (int t = 0; t < NBINS; ++t) {
      double v = active ? sicv[r * NBINS + t] : -1.0;
      bool upd = active && !stopped && (v > maxicv);  // NaN -> false, like ref
      if (upd) { maxicv = v; best = (double)(t + 1) * w; }
      unsigned long long bal = __ballot(upd);
      if (bal != 0ull) no_upd = 0; else ++no_upd;     // global "any row updated"
      if (no_upd >= MAX_TRY) stopped = true;
    }
    if (active) finalt[r] = best + (double)__uint_as_float(~minnot[r]);
  }
}

__global__ __launch_bounds__(256) void k_out(const float* __restrict__ x,
                                             const double* __restrict__ finalt,
                                             float* __restrict__ out) {
  size_t i = (size_t)blockIdx.x * blockDim.x + threadIdx.x;
  size_t stride = (size_t)gridDim.x * blockDim.x;
  const float4* xin = (const float4*)x;
  float4* o = (float4*)out;
  size_t n4 = (size_t)ROWS * NPIX / 4;
  for (; i < n4; i += stride) {
    int row = (int)(i >> 18);  // 2^18 float4 per row
    double ft = finalt[row];
    float4 v = xin[i];
    float4 rr;
    rr.x = ((double)v.x < ft) ? 0.0f : v.x;
    rr.y = ((double)v.y < ft) ? 0.0f : v.y;
    rr.z = ((double)v.z < ft) ? 0.0f : v.z;
    rr.w = ((double)v.w < ft) ? 0.0f : v.w;
    o[i] = rr;
  }
}

extern "C" void kernel_launch(void* const* d_in, const int* in_sizes, int n_in,
                              void* d_out, int out_size, void* d_ws, size_t ws_size,
                              hipStream_t stream) {
  const float* x = (const float*)d_in[0];
  float* out = (float*)d_out;
  char* ws = (char*)d_ws;
  unsigned* minnot = (unsigned*)(ws + OFF_MINNOT);
  unsigned* maxb = (unsigned*)(ws + OFF_MAXB);
  double* finalt = (double*)(ws + OFF_FINAL);
  unsigned* gcnt = (unsigned*)(ws + OFF_CNT);
  int* gcor = (int*)(ws + OFF_COR);
  unsigned long long* gs1 = (unsigned long long*)(ws + OFF_S1);
  unsigned long long* gs2 = (unsigned long long*)(ws + OFF_S2);

  hipMemsetAsync(d_ws, 0, WS_TOTAL, stream);
  k_minmax<<<ROWS * BPR, 256, 0, stream>>>(x, minnot, maxb);
  k_hist<<<ROWS * BPR, 256, 0, stream>>>(x, minnot, maxb, gcnt, gcor, gs1, gs2);
  k_icv_scan<<<1, 1024, 0, stream>>>(gcnt, gcor, gs1, gs2, minnot, maxb, finalt);
  k_out<<<3072, 256, 0, stream>>>(x, finalt, out);
}

// Round 3
// 137.141 us; speedup vs baseline: 1.1105x; 1.0182x over previous
//
#include <hip/hip_runtime.h>
#include <stdint.h>

// Otsu-variant threshold, 24 rows x 2^20 px, f32 in/out.
// f64-exact emulation of the np (float64) reference. Per-bin sums via
// delta-decomposition: xs = fl(j*w) + delta (delta exact by Sterbenz), with
// (count<<44)|round(delta*2^44) and round(delta^2*2^52) in two u64 LDS atomics.

#define ROWS 24
#define NPIX (1 << 20)
#define NBINS 256
#define BPR 64                      // blocks per row
#define CHUNK (NPIX / BPR)          // 16384 elems per block
#define MAX_TRY 25                  // int(256*0.1)

static constexpr double kD1Scale = 17592186044416.0;        // 2^44
static constexpr double kD1Inv   = 1.0 / 17592186044416.0;  // 2^-44
static constexpr double kD2Scale = 4503599627370496.0;      // 2^52
static constexpr double kD2Inv   = 1.0 / 4503599627370496.0;
static constexpr double Nd = 1048576.0;

// ws layout (bytes); [0, OFF_ICV) is memset(0) each call
#define OFF_MINNOT 0                 // u32[24]: atomicMax of ~float_bits
#define OFF_MAXB   128               // u32[24]: atomicMax of float_bits
#define OFF_FINAL  256               // double[24]
#define OFF_CNT    512               // u32 [24][256] counts keyed by j
#define OFF_COR    (OFF_CNT + ROWS*NBINS*4)   // i32 [24][256] floor-bin corr
#define OFF_D1     (OFF_COR + ROWS*NBINS*4)   // u64: sum round(delta*2^44)
#define OFF_D2     (OFF_D1 + ROWS*NBINS*8)    // u64: sum round(delta^2*2^52)
#define OFF_ICV    (OFF_D2 + ROWS*NBINS*8)    // double [24][256]
#define WS_TOTAL   (OFF_ICV + ROWS*NBINS*8)

__device__ __forceinline__ double wave_gmax(const unsigned* __restrict__ minnot,
                                            const unsigned* __restrict__ maxb,
                                            int lane) {
  double d = 0.0;
  if (lane < ROWS) {
    d = (double)__uint_as_float(maxb[lane]) - (double)__uint_as_float(~minnot[lane]);
  }
  for (int o = 16; o; o >>= 1) d = fmax(d, __shfl_down(d, o));
  return d;  // valid in lane 0
}

__global__ __launch_bounds__(256) void k_minmax(const float* __restrict__ x,
                                                unsigned* __restrict__ minnot,
                                                unsigned* __restrict__ maxb) {
  int row = blockIdx.x / BPR;
  int sub = blockIdx.x % BPR;
  const float4* p = (const float4*)(x + (size_t)row * NPIX + (size_t)sub * CHUNK);
  float mn = 3.4e38f, mx = 0.0f;
  for (int i = threadIdx.x; i < CHUNK / 4; i += 256) {
    float4 v = p[i];
    mn = fminf(mn, fminf(fminf(v.x, v.y), fminf(v.z, v.w)));
    mx = fmaxf(mx, fmaxf(fmaxf(v.x, v.y), fmaxf(v.z, v.w)));
  }
  __shared__ float smn[4], smx[4];
  for (int o = 32; o; o >>= 1) {
    mn = fminf(mn, __shfl_down(mn, o));
    mx = fmaxf(mx, __shfl_down(mx, o));
  }
  int wave = threadIdx.x >> 6;
  if ((threadIdx.x & 63) == 0) { smn[wave] = mn; smx[wave] = mx; }
  __syncthreads();
  if (threadIdx.x == 0) {
    for (int w = 1; w < 4; ++w) { mn = fminf(mn, smn[w]); mx = fmaxf(mx, smx[w]); }
    atomicMax(&minnot[row], ~__float_as_uint(mn));  // x>=0: bits order like floats
    atomicMax(&maxb[row], __float_as_uint(mx));
  }
}

__global__ __launch_bounds__(256) void k_hist(const float* __restrict__ x,
    const unsigned* __restrict__ minnot, const unsigned* __restrict__ maxb,
    unsigned* __restrict__ gcnt, int* __restrict__ gcor,
    unsigned long long* __restrict__ gD1, unsigned long long* __restrict__ gD2) {
  __shared__ unsigned long long hA[NBINS], hB[NBINS];
  __shared__ int hcor[NBINS];
  __shared__ double s_w, s_rmin;
  int t = threadIdx.x;
  hA[t] = 0ull; hB[t] = 0ull; hcor[t] = 0;
  int row = blockIdx.x / BPR;
  int sub = blockIdx.x % BPR;
  if (t < 64) {
    double g = wave_gmax(minnot, maxb, t);
    if (t == 0) {
      s_w = g / 256.0;  // exact pow2 scale == reference gmax/NBINS
      s_rmin = (double)__uint_as_float(~minnot[row]);
    }
  }
  __syncthreads();
  double w = s_w, rmin = s_rmin;
  double rw = 1.0 / w;
  const float4* p = (const float4*)(x + (size_t)row * NPIX + (size_t)sub * CHUNK);
  for (int i = threadIdx.x; i < CHUNK / 4; i += 256) {
    float4 v = p[i];
    float vv[4] = {v.x, v.y, v.z, v.w};
#pragma unroll
    for (int c = 0; c < 4; ++c) {
      double xs = (double)vv[c] - rmin;      // exact in f64
      // q == fl64(xs/w) to ~1 ulp via refined reciprocal-mul (div is slow)
      double q1 = xs * rw;
      double rres = fma(-q1, w, xs);
      double q = fma(rres, rw, q1);
      int b = (int)q;                        // q>=0: trunc == floor
      b = b > 255 ? 255 : b;
      double elo = (double)b * w;            // == thresh[b-1] (exact recompute)
      double ehi = (double)(b + 1) * w;      // == thresh[b]
      int j = b;
      double off = elo;
      if (xs > ehi) { if (b < 255) { j = b + 1; off = ehi; } }
      else if (b > 0 && xs <= elo) { j = b - 1; off = (double)j * w; }
      if (j != b) {                          // exact-boundary cases only (rare)
        atomicAdd(&hcor[b], 1);
        atomicAdd(&hcor[j], -1);
      }
      double delta = xs - off;               // exact (Sterbenz)
      unsigned long long d1 = (unsigned long long)llrint(delta * kD1Scale);
      unsigned long long d2 = (unsigned long long)llrint(delta * delta * kD2Scale);
      atomicAdd(&hA[j], (1ull << 44) | d1);  // count in high bits, no carry
      atomicAdd(&hB[j], d2);
    }
  }
  __syncthreads();
  unsigned long long a = hA[t];
  unsigned c = (unsigned)(a >> 44);
  if (c) {
    atomicAdd(&gcnt[row * NBINS + t], c);
    atomicAdd(&gD1[row * NBINS + t], a & ((1ull << 44) - 1ull));
  }
  unsigned long long b2 = hB[t];
  if (b2) atomicAdd(&gD2[row * NBINS + t], b2);
  if (hcor[t] != 0) atomicAdd(&gcor[row * NBINS + t], hcor[t]);
}

// 24 blocks: per-row prefix sums + icv per bin.
__global__ __launch_bounds__(256) void k_icv(const unsigned* __restrict__ gcnt,
    const int* __restrict__ gcor,
    const unsigned long long* __restrict__ gD1,
    const unsigned long long* __restrict__ gD2,
    const unsigned* __restrict__ minnot, const unsigned* __restrict__ maxb,
    double* __restrict__ gicv) {
  __shared__ double sv[NBINS], su[NBINS];
  __shared__ unsigned scnt[NBINS], scntf[NBINS];
  __shared__ double s_w;
  int r = blockIdx.x, t = threadIdx.x;
  if (t < 64) {
    double g = wave_gmax(minnot, maxb, t);
    if (t == 0) s_w = g / 256.0;
  }
  __syncthreads();
  double w = s_w;
  unsigned cnt = gcnt[r * NBINS + t];
  int cor = gcor[r * NBINS + t];
  double d1 = (double)gD1[r * NBINS + t] * kD1Inv;  // sum(delta) in bin t
  double d2 = (double)gD2[r * NBINS + t] * kD2Inv;  // sum(delta^2) in bin t
  double elo = (double)t * w;
  scnt[t] = cnt;
  scntf[t] = cnt + (unsigned)cor;
  sv[t] = (double)cnt * elo + d1;                        // sum(xs) in bin
  su[t] = (double)cnt * (elo * elo) + 2.0 * elo * d1 + d2;  // sum(xs^2)
  __syncthreads();
  for (int o = 1; o < NBINS; o <<= 1) {
    unsigned a0 = 0, a1 = 0; double b0 = 0, b1 = 0;
    if (t >= o) { a0 = scnt[t - o]; a1 = scntf[t - o]; b0 = sv[t - o]; b1 = su[t - o]; }
    __syncthreads();
    if (t >= o) { scnt[t] += a0; scntf[t] += a1; sv[t] += b0; su[t] += b1; }
    __syncthreads();
  }
  const double dNAN = __builtin_nan("");
  double total1 = sv[NBINS - 1], total2 = su[NBINS - 1];
  double mean = total1 / Nd;
  double tot1 = total1 - Nd * mean;
  double tot2 = total2 - Nd * mean * mean;
  double n0 = (double)scnt[t];
  double n1 = Nd - n0;
  double s1raw = sv[t], s2raw = su[t];
  double S1 = s1raw - n0 * mean;
  double S2 = s2raw - 2.0 * mean * s1raw + n0 * mean * mean;
  double mu0 = (scnt[t] > 1u) ? (S2 - S1 * S1 / n0) / (n0 - 1.0) : dNAN;
  double S1b = tot1 - S1, S2b = tot2 - S2;
  double mu1 = (n1 > 1.0) ? (S2b - S1b * S1b / n1) / (n1 - 1.0) : dNAN;
  double w0 = (double)scntf[t] / Nd, w1v = 1.0 - w0;
  double dd = mu0 - mu1;
  gicv[r * NBINS + t] = w0 * w1v * dd * dd;  // NaN propagates (n<=1 cases)
}

__global__ __launch_bounds__(256) void k_scan(const double* __restrict__ gicv,
    const unsigned* __restrict__ minnot, const unsigned* __restrict__ maxb,
    double* __restrict__ finalt) {
  __shared__ double sicv[ROWS * NBINS];  // 48 KB
  __shared__ double s_w;
  int tid = threadIdx.x;
  for (int i = tid; i < ROWS * NBINS; i += 256) sicv[i] = gicv[i];
  if (tid < 64) {
    double g = wave_gmax(minnot, maxb, tid);
    if (tid == 0) s_w = g / 256.0;
  }
  __syncthreads();
  if (tid >= 64) return;
  int r = tid;
  bool active = r < ROWS;
  double w = s_w;
  double maxicv = 0.0, best = 0.0;
  int no_upd = 0;
  bool stopped = false;
  for (int t = 0; t < NBINS; ++t) {
    double v = active ? sicv[r * NBINS + t] : -1.0;
    bool upd = active && !stopped && (v > maxicv);  // NaN -> false, like ref
    if (upd) { maxicv = v; best = (double)(t + 1) * w; }
    unsigned long long bal = __ballot(upd);
    if (bal != 0ull) no_upd = 0; else ++no_upd;     // global "any row updated"
    if (no_upd >= MAX_TRY) stopped = true;
  }
  if (active) finalt[r] = best + (double)__uint_as_float(~minnot[r]);
}

__global__ __launch_bounds__(256) void k_out(const float* __restrict__ x,
                                             const double* __restrict__ finalt,
                                             float* __restrict__ out) {
  size_t i = (size_t)blockIdx.x * blockDim.x + threadIdx.x;
  size_t stride = (size_t)gridDim.x * blockDim.x;
  const float4* xin = (const float4*)x;
  float4* o = (float4*)out;
  size_t n4 = (size_t)ROWS * NPIX / 4;
  for (; i < n4; i += stride) {
    int row = (int)(i >> 18);  // 2^18 float4 per row
    double ft = finalt[row];
    float4 v = xin[i];
    float4 rr;
    rr.x = ((double)v.x < ft) ? 0.0f : v.x;
    rr.y = ((double)v.y < ft) ? 0.0f : v.y;
    rr.z = ((double)v.z < ft) ? 0.0f : v.z;
    rr.w = ((double)v.w < ft) ? 0.0f : v.w;
    o[i] = rr;
  }
}

extern "C" void kernel_launch(void* const* d_in, const int* in_sizes, int n_in,
                              void* d_out, int out_size, void* d_ws, size_t ws_size,
                              hipStream_t stream) {
  const float* x = (const float*)d_in[0];
  float* out = (float*)d_out;
  char* ws = (char*)d_ws;
  unsigned* minnot = (unsigned*)(ws + OFF_MINNOT);
  unsigned* maxb = (unsigned*)(ws + OFF_MAXB);
  double* finalt = (double*)(ws + OFF_FINAL);
  unsigned* gcnt = (unsigned*)(ws + OFF_CNT);
  int* gcor = (int*)(ws + OFF_COR);
  unsigned long long* gD1 = (unsigned long long*)(ws + OFF_D1);
  unsigned long long* gD2 = (unsigned long long*)(ws + OFF_D2);
  double* gicv = (double*)(ws + OFF_ICV);

  hipMemsetAsync(d_ws, 0, OFF_ICV, stream);
  k_minmax<<<ROWS * BPR, 256, 0, stream>>>(x, minnot, maxb);
  k_hist<<<ROWS * BPR, 256, 0, stream>>>(x, minnot, maxb, gcnt, gcor, gD1, gD2);
  k_icv<<<ROWS, 256, 0, stream>>>(gcnt, gcor, gD1, gD2, minnot, maxb, gicv);
  k_scan<<<1, 256, 0, stream>>>(gicv, minnot, maxb, finalt);
  k_out<<<3072, 256, 0, stream>>>(x, finalt, out);
}

// Round 5
// 118.135 us; speedup vs baseline: 1.2891x; 1.1609x over previous
//
#include <hip/hip_runtime.h>
#include <stdint.h>

// Otsu-variant threshold, 24 rows x 2^20 px, f32 in/out.
// f64-exact emulation of the np(float64) reference. Per-bin sums via delta
// decomposition (xs = fl(j*w) + delta, exact by Sterbenz), accumulated as
// fixed-point u64 LDS atomics. R4: fast-path binning (1 mul + frac guard,
// exact f64 div only near boundaries), magic-constant quantization (RNE,
// bit-identical to llrint), memset folded into k_minmax, icv+scan fused with
// mask-based early-stop, pure-f32 output pass with NT stores (ext_vector).

#define ROWS 24
#define NPIX (1 << 20)
#define NBINS 256
#define BPR 64                      // blocks per row
#define CHUNK (NPIX / BPR)          // 16384 elems per block
#define MAX_TRY 25                  // int(256*0.1)

typedef float f32x4 __attribute__((ext_vector_type(4)));

static constexpr double kMagic = 6755399441055744.0;        // 1.5*2^52
static constexpr double kD1Scale = 17592186044416.0;        // 2^44
static constexpr double kD1Inv = 1.0 / 17592186044416.0;
static constexpr double kD2Scale = 4503599627370496.0;      // 2^52
static constexpr double kD2Inv = 1.0 / 4503599627370496.0;
static constexpr double Nd = 1048576.0;
static constexpr double kEps = 1e-9;

// ws layout (bytes). part[] is fully written each call (no init needed);
// [OFF_CNT, WS_END) is zeroed by k_minmax blocks 0..35.
#define OFF_PART  0                 // uint2[1536]: per-block {min_bits,max_bits}
#define OFF_FINAL 12288             // double[24]
#define OFF_T32   12544             // float[24]
#define OFF_CNT   16384             // u32 [24][256] counts keyed by j
#define OFF_COR   40960             // i32 [24][256] floor-bin corrections
#define OFF_D1    65536             // u64 [24][256] sum round(delta*2^44)
#define OFF_D2    114688            // u64 [24][256] sum round(delta^2*2^52)
#define WS_END    163840

// Reduce 1536 per-block partials to per-row min/max bits in LDS.
__device__ __forceinline__ void reduce_minmax(const uint2* __restrict__ part,
                                              unsigned* lmn, unsigned* lmx,
                                              int nthreads) {
  int t = threadIdx.x;
  if (t < ROWS) { lmn[t] = 0xFFFFFFFFu; lmx[t] = 0u; }
  __syncthreads();
  for (int p = t; p < ROWS * BPR; p += nthreads) {
    uint2 v = part[p];
    atomicMin(&lmn[p >> 6], v.x);   // x >= 0: uint bit order == float order
    atomicMax(&lmx[p >> 6], v.y);
  }
  __syncthreads();
}

// First 32 lanes: gmax = max over rows of (max-min); returns w = gmax/256.
__device__ __forceinline__ double compute_w(const unsigned* lmn,
                                            const unsigned* lmx, int t) {
  double d = 0.0;
  if (t < ROWS)
    d = (double)__uint_as_float(lmx[t]) - (double)__uint_as_float(lmn[t]);
  for (int o = 16; o; o >>= 1) d = fmax(d, __shfl_down(d, o));
  return d / 256.0;  // exact pow2 scale; valid in lane 0
}

__global__ __launch_bounds__(256) void k_minmax(const float* __restrict__ x,
                                                uint2* __restrict__ part,
                                                uint4* __restrict__ zero_base) {
  int blk = blockIdx.x;
  if (blk < 36) {  // zero the 147456-byte histogram region (36 * 4 KiB)
    uint4 z; z.x = 0u; z.y = 0u; z.z = 0u; z.w = 0u;
    zero_base[blk * 256 + threadIdx.x] = z;
  }
  int row = blk / BPR, sub = blk % BPR;
  const float4* p = (const float4*)(x + (size_t)row * NPIX + (size_t)sub * CHUNK);
  float mn = 3.4e38f, mx = 0.0f;
  for (int i = threadIdx.x; i < CHUNK / 4; i += 256) {
    float4 v = p[i];
    mn = fminf(mn, fminf(fminf(v.x, v.y), fminf(v.z, v.w)));
    mx = fmaxf(mx, fmaxf(fmaxf(v.x, v.y), fmaxf(v.z, v.w)));
  }
  __shared__ float smn[4], smx[4];
  for (int o = 32; o; o >>= 1) {
    mn = fminf(mn, __shfl_down(mn, o));
    mx = fmaxf(mx, __shfl_down(mx, o));
  }
  int wave = threadIdx.x >> 6;
  if ((threadIdx.x & 63) == 0) { smn[wave] = mn; smx[wave] = mx; }
  __syncthreads();
  if (threadIdx.x == 0) {
    for (int w = 1; w < 4; ++w) { mn = fminf(mn, smn[w]); mx = fmaxf(mx, smx[w]); }
    uint2 r; r.x = __float_as_uint(mn); r.y = __float_as_uint(mx);
    part[blk] = r;
  }
}

__global__ __launch_bounds__(256) void k_hist(const float* __restrict__ x,
    const uint2* __restrict__ part,
    unsigned* __restrict__ gcnt, int* __restrict__ gcor,
    unsigned long long* __restrict__ gD1, unsigned long long* __restrict__ gD2) {
  __shared__ unsigned lmn[ROWS], lmx[ROWS];
  __shared__ unsigned long long hA[NBINS], hB[NBINS];
  __shared__ int hcor[NBINS];
  __shared__ double s_w, s_rmin;
  int t = threadIdx.x;
  int row = blockIdx.x / BPR, sub = blockIdx.x % BPR;
  hA[t] = 0ull; hB[t] = 0ull; hcor[t] = 0;
  reduce_minmax(part, lmn, lmx, 256);
  if (t < 32) {
    double wv = compute_w(lmn, lmx, t);
    if (t == 0) { s_w = wv; s_rmin = (double)__uint_as_float(lmn[row]); }
  }
  __syncthreads();
  double w = s_w, rmin = s_rmin, rw = 1.0 / w;
  const float4* p = (const float4*)(x + (size_t)row * NPIX + (size_t)sub * CHUNK);
  for (int i = t; i < CHUNK / 4; i += 256) {
    float4 v = p[i];
    float vv[4] = {v.x, v.y, v.z, v.w};
#pragma unroll
    for (int c = 0; c < 4; ++c) {
      double xs = (double)vv[c] - rmin;  // exact in f64
      double q1 = xs * rw;
      int b = (int)q1;
      double fr = q1 - (double)b;
      int j; double off;
      if (__builtin_expect(fr >= kEps && fr <= 1.0 - kEps && b <= 255, 1)) {
        // margin 1e-9 >> 5.7e-14 total rounding error => b == floor(fl64(xs/w))
        // and xs strictly inside (thresh[b-1], thresh[b]) => j == b.
        j = b; off = (double)b * w;
      } else {
        double q = xs / w;               // exact reference semantics
        b = (int)q; if (b > 255) b = 255;
        double elo = (double)b * w, ehi = (double)(b + 1) * w;
        j = b; off = elo;
        if (xs > ehi) { if (b < 255) { j = b + 1; off = ehi; } }
        else if (b > 0 && xs <= elo) { j = b - 1; off = (double)j * w; }
        if (j != b) { atomicAdd(&hcor[b], 1); atomicAdd(&hcor[j], -1); }
      }
      double delta = xs - off;           // exact (Sterbenz), >= 0
      double t1 = fma(delta, kD1Scale, kMagic);          // RNE == llrint
      double dd = delta * delta;
      double t2 = fma(dd, kD2Scale, kMagic);
      unsigned long long d1 = (unsigned long long)__double_as_longlong(t1)
                              & 0x0007FFFFFFFFFFFFull;
      unsigned long long d2 = (unsigned long long)__double_as_longlong(t2)
                              & 0x0007FFFFFFFFFFFFull;
      atomicAdd(&hA[j], d1 | (1ull << 44));  // count in bits 44+ (sum d1 < 2^44)
      atomicAdd(&hB[j], d2);
    }
  }
  __syncthreads();
  unsigned long long a = hA[t];
  unsigned c = (unsigned)(a >> 44);
  int base = row * NBINS + t;
  if (c) {
    atomicAdd(&gcnt[base], c);
    atomicAdd(&gD1[base], a & ((1ull << 44) - 1ull));
  }
  if (hB[t]) atomicAdd(&gD2[base], hB[t]);
  if (hcor[t]) atomicAdd(&gcor[base], hcor[t]);
}

// One block, 1024 threads: icv for all 24 rows (wave-parallel prefix sums),
// mask-based early-stop scan, final thresholds (f64 + rounded-up f32).
__global__ __launch_bounds__(1024) void k_icv_scan(
    const unsigned* __restrict__ gcnt, const int* __restrict__ gcor,
    const unsigned long long* __restrict__ gD1,
    const unsigned long long* __restrict__ gD2,
    const uint2* __restrict__ part,
    double* __restrict__ finalt, float* __restrict__ t32g) {
  __shared__ unsigned lmn[ROWS], lmx[ROWS];
  __shared__ unsigned long long umask[ROWS][4];
  __shared__ unsigned long long ganyw[4];
  __shared__ double s_w;
  __shared__ int s_tstop;
  int t = threadIdx.x;
  if (t < 4) ganyw[t] = 0ull;
  if (t < ROWS * 4) ((unsigned long long*)umask)[t] = 0ull;
  reduce_minmax(part, lmn, lmx, 1024);
  if (t < 32) {
    double wv = compute_w(lmn, lmx, t);
    if (t == 0) s_w = wv;
  }
  __syncthreads();
  double w = s_w;
  int wave = t >> 6, lane = t & 63;
  const double dNAN = __builtin_nan("");

  for (int pass = 0; pass < 2; ++pass) {
    if (pass == 1 && wave >= 8) break;   // no __syncthreads inside this loop
    int r = pass ? 16 + wave : wave;
    // lane handles bins {lane, 64+lane, 128+lane, 192+lane}
    double e1[4], e2[4];
    unsigned long long pc0[4];
#pragma unroll
    for (int k = 0; k < 4; ++k) {
      int bin = k * 64 + lane;
      int idx = r * NBINS + bin;
      unsigned n = gcnt[idx];
      int cor = gcor[idx];
      double d1 = (double)gD1[idx] * kD1Inv;   // sum(delta) in bin
      double d2v = (double)gD2[idx] * kD2Inv;  // sum(delta^2) in bin
      double elo = (double)bin * w;
      e1[k] = (double)n * elo + d1;                          // sum(xs)
      e2[k] = (double)n * (elo * elo) + 2.0 * elo * d1 + d2v;  // sum(xs^2)
      pc0[k] = (unsigned long long)n |
               ((unsigned long long)(unsigned)(n + (unsigned)cor) << 32);
    }
    // inclusive prefix sums over bins: 4 wave scans with carry
    double c1 = 0.0, c2 = 0.0;
    unsigned long long cc = 0ull;
    double E1[4], E2[4];
    unsigned long long CC[4];
#pragma unroll
    for (int k = 0; k < 4; ++k) {
      double p1 = e1[k], p2 = e2[k];
      unsigned long long pc = pc0[k];
      for (int o = 1; o < 64; o <<= 1) {
        double u1 = __shfl_up(p1, o), u2 = __shfl_up(p2, o);
        unsigned long long uc = __shfl_up(pc, o);
        if (lane >= o) { p1 += u1; p2 += u2; pc += uc; }
      }
      E1[k] = p1 + c1; E2[k] = p2 + c2; CC[k] = pc + cc;
      c1 += __shfl(p1, 63); c2 += __shfl(p2, 63); cc += __shfl(pc, 63);
    }
    double total1 = c1, total2 = c2;
    double mean = total1 / Nd;
    double tot1 = total1 - Nd * mean;
    double tot2 = total2 - Nd * mean * mean;
    double icv4[4];
#pragma unroll
    for (int k = 0; k < 4; ++k) {
      unsigned n0i = (unsigned)(CC[k] & 0xffffffffull);
      double n0 = (double)n0i;
      double n1 = Nd - n0;
      double s1raw = E1[k], s2raw = E2[k];
      double S1 = s1raw - n0 * mean;
      double S2 = s2raw - 2.0 * mean * s1raw + n0 * mean * mean;
      double mu0 = (n0i > 1u) ? (S2 - S1 * S1 / n0) / (n0 - 1.0) : dNAN;
      double S1b = tot1 - S1, S2b = tot2 - S2;
      double mu1 = (n1 > 1.0) ? (S2b - S1b * S1b / n1) / (n1 - 1.0) : dNAN;
      double w0 = (double)(unsigned)(CC[k] >> 32) / Nd, w1v = 1.0 - w0;
      double ddv = mu0 - mu1;
      icv4[k] = w0 * w1v * ddv * ddv;   // NaN propagates (n<=1 cases)
    }
    // update bits: U[t] = icv[t] > max(0, nanmax(icv[0..t-1]))
    double m = 0.0;
    unsigned long long myMask[4];
#pragma unroll
    for (int k = 0; k < 4; ++k) {
      double v = icv4[k];
      double pm = v;  // inclusive prefix-max (fmax drops NaN)
      for (int o = 1; o < 64; o <<= 1) {
        double u = __shfl_up(pm, o);
        if (lane >= o) pm = fmax(pm, u);
      }
      double excl = __shfl_up(pm, 1);
      double Mprev = (lane == 0) ? m : fmax(m, excl);
      bool upd = v > Mprev;             // NaN v -> false, like reference
      myMask[k] = __ballot(upd);
      m = fmax(m, __shfl(pm, 63));
    }
    if (lane == 0) {
#pragma unroll
      for (int k = 0; k < 4; ++k) {
        umask[r][k] = myMask[k];
        atomicOr(&ganyw[k], myMask[k]);
      }
    }
  }
  __syncthreads();
  if (t == 0) {
    // reference scan: no_upd counts consecutive bins with no global update;
    // stopped when it reaches MAX_TRY => updates allowed for bins <= t_stop.
    int no_upd = 0, tstop = 255;
    for (int b = 0; b < 256; ++b) {
      bool any = (ganyw[b >> 6] >> (b & 63)) & 1ull;
      if (any) no_upd = 0; else ++no_upd;
      if (no_upd >= MAX_TRY) { tstop = b; break; }
    }
    s_tstop = tstop;
  }
  __syncthreads();
  if (t < ROWS) {
    int tstop = s_tstop;
    int tbest = -1;
    for (int k = 3; k >= 0; --k) {
      unsigned long long msk = umask[t][k];
      int hi = k * 64 + 63;
      if (hi > tstop) {
        int shift = tstop - k * 64;
        if (shift < 0) msk = 0ull;
        else msk &= (shift >= 63) ? ~0ull : ((2ull << shift) - 1ull);
      }
      if (msk) { tbest = k * 64 + 63 - __clzll(msk); break; }
    }
    double rmin = (double)__uint_as_float(lmn[t]);
    double ft = (tbest >= 0) ? (double)(tbest + 1) * w + rmin : rmin;
    finalt[t] = ft;
    // t32 = smallest f32 >= ft  (then f32 x < t32  <=>  (f64)x < ft)
    float f = (float)ft;
    if ((double)f < ft) f = __uint_as_float(__float_as_uint(f) + 1u);
    t32g[t] = f;
  }
}

__global__ __launch_bounds__(256) void k_out(const float* __restrict__ x,
                                             const float* __restrict__ t32g,
                                             float* __restrict__ out) {
  size_t i = (size_t)blockIdx.x * blockDim.x + threadIdx.x;
  size_t stride = (size_t)gridDim.x * blockDim.x;
  const f32x4* xin = (const f32x4*)x;
  f32x4* o = (f32x4*)out;
  size_t n4 = (size_t)ROWS * NPIX / 4;
  for (; i < n4; i += stride) {
    float ft = t32g[i >> 18];  // 2^18 float4 per row
    f32x4 v = xin[i];
    f32x4 rr;
    rr.x = (v.x < ft) ? 0.0f : v.x;
    rr.y = (v.y < ft) ? 0.0f : v.y;
    rr.z = (v.z < ft) ? 0.0f : v.z;
    rr.w = (v.w < ft) ? 0.0f : v.w;
    __builtin_nontemporal_store(rr, &o[i]);
  }
}

extern "C" void kernel_launch(void* const* d_in, const int* in_sizes, int n_in,
                              void* d_out, int out_size, void* d_ws, size_t ws_size,
                              hipStream_t stream) {
  const float* x = (const float*)d_in[0];
  float* out = (float*)d_out;
  char* ws = (char*)d_ws;
  uint2* part = (uint2*)(ws + OFF_PART);
  double* finalt = (double*)(ws + OFF_FINAL);
  float* t32g = (float*)(ws + OFF_T32);
  unsigned* gcnt = (unsigned*)(ws + OFF_CNT);
  int* gcor = (int*)(ws + OFF_COR);
  unsigned long long* gD1 = (unsigned long long*)(ws + OFF_D1);
  unsigned long long* gD2 = (unsigned long long*)(ws + OFF_D2);

  k_minmax<<<ROWS * BPR, 256, 0, stream>>>(x, part, (uint4*)(ws + OFF_CNT));
  k_hist<<<ROWS * BPR, 256, 0, stream>>>(x, part, gcnt, gcor, gD1, gD2);
  k_icv_scan<<<1, 1024, 0, stream>>>(gcnt, gcor, gD1, gD2, part, finalt, t32g);
  k_out<<<3072, 256, 0, stream>>>(x, t32g, out);
}